// Round 1
// baseline (335.659 us; speedup 1.0000x reference)
//
#include <hip/hip_runtime.h>

// N=100000 nodes, M=800000 edges, F_IN=64, F_E=16, H=64, T_NODE=2, T_EDGE=3.
// score == softmax over singleton axis == 1.0 exactly, so h3/h4/num are dead:
//   out[n] = h1[n] + sum_{e: dst=n} ( h2[src_e] + ef_e . W5[t_e] + b5[t_e] )
//
// R8: K1 unchanged (parity-interleaved gemm/scatter). K2 reworked for issue
// throughput: W5 transposed to lane-major LDS ([h][52], col 51 zero) so the
// per-dst 51x64 matvec is 13 ds_read_b128 pairs instead of 51 scalar b32;
// edge-loop tail predication replaced by one duplicate-subtract correction.

#define CAP 16
#define OVF_CAP 32768

typedef __attribute__((ext_vector_type(8))) short short8;
typedef __attribute__((ext_vector_type(4))) float f32x4;

__device__ __forceinline__ float b2f(unsigned short u) {
    union { unsigned v; float f; } x; x.v = ((unsigned)u) << 16; return x.f;
}
__device__ __forceinline__ unsigned short f2b(float f) {
    union { float f; unsigned v; } x; x.f = f;
    unsigned u = x.v;
    unsigned r = (u + 0x7FFFu + ((u >> 16) & 1u)) >> 16;
    return (unsigned short)r;
}

// ---------------- K1: gemm (even blocks) || slot scatter (odd blocks) -------
__global__ __launch_bounds__(256) void k1_gemm_scatter(
    const float* __restrict__ x, const int* __restrict__ nt,
    const float* __restrict__ W1, const float* __restrict__ b1,
    const float* __restrict__ W2, const float* __restrict__ b2,
    const int* __restrict__ esrc, const int* __restrict__ edst,
    const int* __restrict__ etype,
    int* __restrict__ cnt32, int* __restrict__ ovfCnt,
    int4* __restrict__ ovf, int2* __restrict__ rec,
    float* __restrict__ out, unsigned short* __restrict__ h2b,
    int N, int M)
{
    // 72 = 64 + 8 pad: row stride 144 B -> 2-way bank alias (free)
    __shared__ __align__(16) unsigned short sx[128 * 72];     // 18 KB
    __shared__ __align__(16) unsigned short sw[4][64 * 72];   // 36 KB
    __shared__ int snt[128];

    int tid = threadIdx.x;

    if (blockIdx.x & 1) {
        // ---------------- scatter path: 1024 edges/block, 4 per thread ------
        int e0 = (blockIdx.x >> 1) * 1024 + tid;
        int dd[4], ssrc[4], tty[4];
        bool v[4];
#pragma unroll
        for (int j = 0; j < 4; ++j) {
            int e = e0 + j * 256;
            v[j] = e < M;
            int ec = v[j] ? e : 0;
            dd[j]   = edst[ec];
            ssrc[j] = esrc[ec];
            tty[j]  = etype[ec];
        }
        int pos[4];
#pragma unroll
        for (int j = 0; j < 4; ++j)
            if (v[j]) pos[j] = atomicAdd(&cnt32[dd[j]], 1);
#pragma unroll
        for (int j = 0; j < 4; ++j) {
            if (!v[j]) continue;
            int packed = ssrc[j] | (tty[j] << 20);
            int e = e0 + j * 256;
            if (pos[j] < CAP) {
                rec[dd[j] * CAP + pos[j]] = make_int2(packed, e);
            } else {
                int slot = atomicAdd(ovfCnt, 1);
                if (slot < OVF_CAP) ovf[slot] = make_int4(packed, e, dd[j], 0);
            }
        }
        return;
    }

    // ---------------- gemm path: 128 rows x 64 h, 4 weight mats -------------
    int rowbase = (blockIdx.x >> 1) * 128;

    const float* Wm0 = W1;            // [k][n] fp32, type 0
    const float* Wm1 = W1 + 4096;     // type 1
    const float* Wm2 = W2;
    const float* Wm3 = W2 + 4096;
#pragma unroll
    for (int j = 0; j < 4; ++j) {
        int k  = (tid >> 4) + j * 16;
        int n4 = (tid & 15) * 4;
        float4 w0 = *(const float4*)&Wm0[k * 64 + n4];
        float4 w1v = *(const float4*)&Wm1[k * 64 + n4];
        float4 w2v = *(const float4*)&Wm2[k * 64 + n4];
        float4 w3 = *(const float4*)&Wm3[k * 64 + n4];
        sw[0][(n4 + 0) * 72 + k] = f2b(w0.x);
        sw[0][(n4 + 1) * 72 + k] = f2b(w0.y);
        sw[0][(n4 + 2) * 72 + k] = f2b(w0.z);
        sw[0][(n4 + 3) * 72 + k] = f2b(w0.w);
        sw[1][(n4 + 0) * 72 + k] = f2b(w1v.x);
        sw[1][(n4 + 1) * 72 + k] = f2b(w1v.y);
        sw[1][(n4 + 2) * 72 + k] = f2b(w1v.z);
        sw[1][(n4 + 3) * 72 + k] = f2b(w1v.w);
        sw[2][(n4 + 0) * 72 + k] = f2b(w2v.x);
        sw[2][(n4 + 1) * 72 + k] = f2b(w2v.y);
        sw[2][(n4 + 2) * 72 + k] = f2b(w2v.z);
        sw[2][(n4 + 3) * 72 + k] = f2b(w2v.w);
        sw[3][(n4 + 0) * 72 + k] = f2b(w3.x);
        sw[3][(n4 + 1) * 72 + k] = f2b(w3.y);
        sw[3][(n4 + 2) * 72 + k] = f2b(w3.z);
        sw[3][(n4 + 3) * 72 + k] = f2b(w3.w);
    }

    if (tid < 128) {
        int r = rowbase + tid;
        snt[tid] = (r < N) ? nt[r] : 0;
    }

    // stage x tile (contiguous rows, no perm)
    int fr = (tid & 15) * 4;
    int ir = tid >> 4;
#pragma unroll
    for (int it = 0; it < 8; ++it) {
        int i = it * 16 + ir;
        int r = rowbase + i;
        float4 v = make_float4(0.f, 0.f, 0.f, 0.f);
        if (r < N) v = *(const float4*)&x[(size_t)r * 64 + fr];
        ushort4 p;
        p.x = f2b(v.x); p.y = f2b(v.y); p.z = f2b(v.z); p.w = f2b(v.w);
        *(ushort4*)&sx[i * 72 + fr] = p;
    }
    __syncthreads();

    int lane = tid & 63;
    int wid  = tid >> 6;
    int q    = lane >> 4;
    int cc   = lane & 15;
    int m0   = wid * 32;

    f32x4 acc[4][2][4];   // [mat][s][t]
#pragma unroll
    for (int mm = 0; mm < 4; ++mm)
#pragma unroll
        for (int s = 0; s < 2; ++s)
#pragma unroll
            for (int t = 0; t < 4; ++t)
                acc[mm][s][t] = (f32x4){0.f, 0.f, 0.f, 0.f};

#pragma unroll
    for (int k0 = 0; k0 < 64; k0 += 32) {
        int ko = k0 + q * 8;
        short8 af0 = *(short8*)&sx[(m0 + cc) * 72 + ko];
        short8 af1 = *(short8*)&sx[(m0 + 16 + cc) * 72 + ko];
#pragma unroll
        for (int mm = 0; mm < 4; ++mm)
#pragma unroll
            for (int t = 0; t < 4; ++t) {
                short8 bf = *(short8*)&sw[mm][(t * 16 + cc) * 72 + ko];
                acc[mm][0][t] = __builtin_amdgcn_mfma_f32_16x16x32_bf16(
                    af0, bf, acc[mm][0][t], 0, 0, 0);
                acc[mm][1][t] = __builtin_amdgcn_mfma_f32_16x16x32_bf16(
                    af1, bf, acc[mm][1][t], 0, 0, 0);
            }
    }

    float b1v[2][4], b2v[2][4];
#pragma unroll
    for (int ty = 0; ty < 2; ++ty)
#pragma unroll
        for (int t = 0; t < 4; ++t) {
            b1v[ty][t] = b1[ty * 64 + t * 16 + cc];
            b2v[ty][t] = b2[ty * 64 + t * 16 + cc];
        }

    // C/D layout: col = lane&15, row = quad*4 + reg
#pragma unroll
    for (int s = 0; s < 2; ++s)
#pragma unroll
        for (int reg = 0; reg < 4; ++reg) {
            int rl = m0 + s * 16 + q * 4 + reg;
            int r = rowbase + rl;
            if (r < N) {
                int ty = snt[rl];
#pragma unroll
                for (int t = 0; t < 4; ++t) {
                    float v1 = (ty ? acc[1][s][t][reg] : acc[0][s][t][reg])
                               + b1v[ty][t];
                    float v2 = (ty ? acc[3][s][t][reg] : acc[2][s][t][reg])
                               + b2v[ty][t];
                    out[(size_t)r * 64 + t * 16 + cc] = v1;
                    h2b[(size_t)r * 64 + t * 16 + cc] = f2b(v2);
                }
            }
        }
}

// ---------------- K2: gather (one wave per dst) + overflow fixup tail -------
// lane roles in edge loop: all lanes accH += h2b[src][lane];
//   lanes 0..47: accS += (etype == lane>>4) ? ef[edge][lane&15] : 0
//   lanes 48..50: accS += (etype == lane-48) ? 1 : 0
// epilogue: out[d] += accH + 52x64 matvec of accS against lane-major sWt
// ([W5;b5;0] transposed, 13 float4 LDS reads per operand, conflict-free at
// row stride 52 floats). Edge-loop tail handled by duplicate-subtract.
__global__ __launch_bounds__(256) void k2_gather(
    const float* __restrict__ ef, const int2* __restrict__ rec,
    const int* __restrict__ cnt32,
    const float* __restrict__ W5, const float* __restrict__ b5,
    const int4* __restrict__ ovf, const int* __restrict__ ovfCnt,
    const unsigned short* __restrict__ h2b, float* __restrict__ out,
    int N, int gatherBlocks, int ovfBlocks)
{
    __shared__ __align__(16) float sWt[64 * 52];  // [h][j], col 51 = 0
    __shared__ __align__(16) float sG[4][64];

    int tid = threadIdx.x;
    // stage transposed: source reads coalesced, j = row of [W5;b5]
    for (int i = tid; i < 3264; i += 256) {       // 3264 = 51*64
        int j = i >> 6;                           // 0..50
        int h = i & 63;
        float v = (j < 48) ? W5[i] : b5[i - 3072];
        sWt[h * 52 + j] = v;
    }
    if (tid < 64) sWt[tid * 52 + 51] = 0.f;       // zero-pad column
    __syncthreads();

    int lane = tid & 63;
    int wid = tid >> 6;

    if (blockIdx.x >= (unsigned)gatherBlocks) {
        // ---- overflow fixup: grid-stride waves over ovf list (rare) ----
        int novf = min(*ovfCnt, OVF_CAP);
        int gw = (blockIdx.x - gatherBlocks) * 4 + wid;
        int nw = ovfBlocks * 4;
        for (int ri = gw; ri < novf; ri += nw) {
            int4 o = ovf[ri];
            int s = o.x & 0xFFFFF;
            int t = (unsigned)o.x >> 20;
            float acc = sWt[lane * 52 + 48 + t] +
                        b2f(h2b[((size_t)s << 6) | lane]);
            const float4* e4 = (const float4*)&ef[(size_t)o.y * 16];
            const float4* wt = (const float4*)&sWt[lane * 52 + t * 16];
#pragma unroll
            for (int f4 = 0; f4 < 4; ++f4) {
                float4 e = e4[f4];
                float4 w = wt[f4];
                acc = fmaf(e.x, w.x, acc);
                acc = fmaf(e.y, w.y, acc);
                acc = fmaf(e.z, w.z, acc);
                acc = fmaf(e.w, w.w, acc);
            }
            unsafeAtomicAdd(&out[(size_t)o.z * 64 + lane], acc);
        }
        return;
    }

    int d = blockIdx.x * 4 + wid;
    bool active = d < N;
    int deg = 0;
    if (active) deg = min(cnt32[d], CAP);
    unsigned base = (unsigned)d * CAP;

    int myt = (lane < 48) ? (lane >> 4) : (lane - 48);
    unsigned myf = lane & 15;
    bool fl = lane < 48;
    float accH = 0.f, accS = 0.f;
    float hLast = 0.f, vLast = 0.f;
    int tLast = -1;
    int degm1 = deg - 1;

    for (int i = 0; i < deg; i += 8) {
        int2 r[8];
#pragma unroll
        for (int j = 0; j < 8; ++j) {
            int ij = min(i + j, degm1);           // clamp to written slots
            r[j] = rec[base + ij];
        }
        float hv[8], ev[8];
#pragma unroll
        for (int j = 0; j < 8; ++j) {
            unsigned s = (unsigned)r[j].x & 0xFFFFFu;
            hv[j] = b2f(h2b[((size_t)s << 6) | (unsigned)lane]);
            ev[j] = ef[((unsigned)r[j].y << 4) | myf];
        }
#pragma unroll
        for (int j = 0; j < 8; ++j) {
            int t = (int)((unsigned)r[j].x >> 20);
            float v = fl ? ev[j] : 1.0f;
            accH += hv[j];
            accS += (t == myt) ? v : 0.f;
            hLast = hv[j]; vLast = v; tLast = t;  // dead except final j
        }
    }
    // slots past deg re-read record deg-1: subtract the duplicates once
    float fd = (float)(((deg + 7) & ~7) - deg);
    accH -= fd * hLast;
    accS -= (tLast == myt) ? fd * vLast : 0.f;

    sG[wid][lane] = accS;                          // sG[wid][51] == 0
    float rr = accH;
    const float4* g4 = (const float4*)sG[wid];     // broadcast reads
    const float4* w4 = (const float4*)&sWt[lane * 52];
#pragma unroll
    for (int j4 = 0; j4 < 13; ++j4) {
        float4 g = g4[j4];
        float4 w = w4[j4];
        rr = fmaf(g.x, w.x, rr);
        rr = fmaf(g.y, w.y, rr);
        rr = fmaf(g.z, w.z, rr);
        rr = fmaf(g.w, w.w, rr);
    }

    if (active)
        unsafeAtomicAdd(&out[((size_t)(unsigned)d << 6) | lane], rr);
}

extern "C" void kernel_launch(void* const* d_in, const int* in_sizes, int n_in,
                              void* d_out, int out_size, void* d_ws, size_t ws_size,
                              hipStream_t stream) {
    const float* x  = (const float*)d_in[0];
    const float* ef = (const float*)d_in[1];
    const int* nt   = (const int*)d_in[2];
    const int* es   = (const int*)d_in[3];
    const int* ed   = (const int*)d_in[4];
    const int* et   = (const int*)d_in[5];
    const float* W1 = (const float*)d_in[6];
    const float* b1 = (const float*)d_in[7];
    const float* W2 = (const float*)d_in[8];
    const float* b2 = (const float*)d_in[9];
    // d_in[10..13] = W3,b3,W4,b4 dead (score == 1.0)
    const float* W5 = (const float*)d_in[14];
    const float* b5 = (const float*)d_in[15];

    int N = in_sizes[2];
    int M = in_sizes[3];

    char* w = (char*)d_ws;
    size_t off = 0;
    unsigned short* h2b = (unsigned short*)(w + off); off += (size_t)N * 64 * 2;  // 12.8 MB
    off = (off + 255) & ~(size_t)255;
    int2* rec = (int2*)(w + off); off += (size_t)N * CAP * 8;                     // 12.8 MB
    off = (off + 255) & ~(size_t)255;
    int4* ovf = (int4*)(w + off); off += (size_t)OVF_CAP * 16;                    // 0.5 MB
    off = (off + 255) & ~(size_t)255;
    // zero block: [ovfCnt:1 int][pad->64 B][cnt32: N ints]
    int* ovfCnt = (int*)(w + off);
    int* cnt32  = (int*)(w + off + 64);
    size_t zeroBytes = 64 + (size_t)N * 4;

    float* out = (float*)d_out;

    hipMemsetAsync(ovfCnt, 0, zeroBytes, stream);

    int gemmBlocks    = (N + 127) / 128;    // 782
    int scatterBlocks = (M + 1023) / 1024;  // 782
    int gb1 = 2 * max(gemmBlocks, scatterBlocks);
    k1_gemm_scatter<<<gb1, 256, 0, stream>>>(
        x, nt, W1, b1, W2, b2, es, ed, et,
        cnt32, ovfCnt, ovf, rec, out, h2b, N, M);

    int gatherBlocks = (N + 3) / 4;
    int ovfBlocks = 32;
    k2_gather<<<gatherBlocks + ovfBlocks, 256, 0, stream>>>(
        ef, rec, cnt32, W5, b5, ovf, ovfCnt, h2b, out,
        N, gatherBlocks, ovfBlocks);
}